// Round 16
// baseline (133.267 us; speedup 1.0000x reference)
//
#include <hip/hip_runtime.h>
#include <stdint.h>

#define DEVFN __device__ __forceinline__

typedef __attribute__((ext_vector_type(8))) __bf16 bf16x8;
typedef __attribute__((ext_vector_type(8))) short short8;
typedef __attribute__((ext_vector_type(4))) float f32x4;
typedef __attribute__((ext_vector_type(4))) unsigned int u32x4;

// Native scalar cast -> hardware v_cvt_pk_bf16_f32 (RNE). (m240: don't
// hand-write bf16 conversion.)
DEVFN unsigned short f2bf(float f) {
  return __builtin_bit_cast(unsigned short, (__bf16)f);
}

// global -> LDS direct copy, 16B per lane. Dest must be linear in lane order.
DEVFN void gload_lds16(const void* g, void* l) {
  __builtin_amdgcn_global_load_lds(
      (const __attribute__((address_space(1))) void*)(uintptr_t)g,
      (__attribute__((address_space(3))) void*)(uint32_t)(uintptr_t)l,
      16, 0, 0);
}

// ---------------- prep kernels ----------------

__global__ void k_cast_x(const float* __restrict__ x, short* __restrict__ xb, int n8) {
  int i = blockIdx.x * blockDim.x + threadIdx.x;
  if (i >= n8) return;
  const f32x4* xf = (const f32x4*)x;
  f32x4 a = xf[2 * i], b = xf[2 * i + 1];
  short8 s;
  s[0] = (short)f2bf(a[0]); s[1] = (short)f2bf(a[1]);
  s[2] = (short)f2bf(a[2]); s[3] = (short)f2bf(a[3]);
  s[4] = (short)f2bf(b[0]); s[5] = (short)f2bf(b[1]);
  s[6] = (short)f2bf(b[2]); s[7] = (short)f2bf(b[3]);
  ((short8*)xb)[i] = s;
}

// w[R][C] (f32) -> wt[C][R] (bf16)
__global__ void k_transpose_bf(const float* __restrict__ w, short* __restrict__ wt, int R, int C) {
  int i = blockIdx.x * blockDim.x + threadIdx.x;
  if (i >= R * C) return;
  int c = i / R, r = i - c * R;
  wt[i] = (short)f2bf(w[(size_t)r * C + c]);
}

// ---------------- GEMM: C[M][N] = A[M][K] * Bt[N][K]^T ----------------
// Block tile 128 x (NB*32), BK=32, 256 threads (4 waves, per-wave 64x(NB*16)).
// 3-buffer LDS pipeline, counted vmcnt; T1 XCD swizzle; T2 slot-swizzle.
// NB=8 for GEMM1 (measured 57.6us, MfmaUtil 27.7%); NB=4 for GEMM2.
// (Round 14/15's fused-cast GEMM1 variant was +24us with an unexplained
// stall -> reverted to this measured-good structure.)

template <int BF16_OUT, int NB>
__global__ __launch_bounds__(256, NB == 8 ? 2 : 3)
void k_gemm(const short* __restrict__ A, const short* __restrict__ Bt,
            unsigned short* __restrict__ Cb, float* __restrict__ Cf,
            const float* __restrict__ bias, int M, int N, int K) {
  constexpr int BN = NB * 32;
  constexpr int BCH = NB / 2;
  __shared__ short As[3][128 * 32];
  __shared__ short Bs[3][BN * 32];
  const int tid = threadIdx.x;
  const int l = tid & 63, w = tid >> 6;
  const int ntile = N / BN;
  const int nwg = gridDim.x, cpx = nwg >> 3;
  const int bid = (blockIdx.x & 7) * cpx + (blockIdx.x >> 3);
  const int mt = bid / ntile, nt = bid % ntile;
  const int m0 = mt << 7, n0 = nt * BN;
  const int wm = (w >> 1) << 6, wn = (w & 1) * (NB * 16);

  f32x4 acc[4][NB];
#pragma unroll
  for (int i = 0; i < 4; i++)
#pragma unroll
    for (int j = 0; j < NB; j++) acc[i][j] = (f32x4){0.f, 0.f, 0.f, 0.f};

  const int nsteps = K >> 5;

  auto stage = [&](int buf, int t) {
#pragma unroll
    for (int c = 0; c < 2; ++c) {
      int ch = tid + c * 256;
      int row = ch >> 2;
      int sl = (ch & 3) ^ ((row >> 1) & 3);
      gload_lds16(A + (size_t)(m0 + row) * K + t * 32 + sl * 8, &As[buf][ch * 8]);
    }
#pragma unroll
    for (int c = 0; c < BCH; ++c) {
      int ch = tid + c * 256;
      int row = ch >> 2;
      int sl = (ch & 3) ^ ((row >> 1) & 3);
      gload_lds16(Bt + (size_t)(n0 + row) * K + t * 32 + sl * 8, &Bs[buf][ch * 8]);
    }
  };
  const int sp8 = (((l >> 4) ^ ((l >> 1) & 3)) << 3);
  auto compute = [&](int buf) {
    bf16x8 af[4], bfr[NB];
#pragma unroll
    for (int i = 0; i < 4; i++)
      af[i] = *(const bf16x8*)&As[buf][(wm + i * 16 + (l & 15)) * 32 + sp8];
#pragma unroll
    for (int j = 0; j < NB; j++)
      bfr[j] = *(const bf16x8*)&Bs[buf][(wn + j * 16 + (l & 15)) * 32 + sp8];
#pragma unroll
    for (int i = 0; i < 4; i++)
#pragma unroll
      for (int j = 0; j < NB; j++)
        acc[i][j] = __builtin_amdgcn_mfma_f32_16x16x32_bf16(af[i], bfr[j], acc[i][j], 0, 0, 0);
  };

  stage(0, 0);
  stage(1, 1);
#pragma unroll 1
  for (int t = 0; t < nsteps; ++t) {
    if (t + 1 < nsteps) {
      if constexpr (NB == 8)
        asm volatile("s_waitcnt vmcnt(6)" ::: "memory");
      else
        asm volatile("s_waitcnt vmcnt(4)" ::: "memory");
    } else {
      asm volatile("s_waitcnt vmcnt(0)" ::: "memory");
    }
    __builtin_amdgcn_sched_barrier(0);
    __builtin_amdgcn_s_barrier();
    __builtin_amdgcn_sched_barrier(0);
    if (t + 2 < nsteps) stage((t + 2) % 3, t + 2);
    compute(t % 3);
  }

#pragma unroll
  for (int i = 0; i < 4; i++) {
    int mrow = m0 + wm + i * 16 + ((l >> 4) << 2);
#pragma unroll
    for (int j = 0; j < NB; j++) {
      int ncol = n0 + wn + j * 16 + (l & 15);
#pragma unroll
      for (int r = 0; r < 4; r++) {
        if (BF16_OUT) {
          Cb[(size_t)(mrow + r) * N + ncol] = f2bf(acc[i][j][r]);
        } else {
          Cf[(size_t)(mrow + r) * N + ncol] = acc[i][j][r] + bias[ncol];
        }
      }
    }
  }
}

// ---------------- fused attention per (bp, head) ----------------
// Swapped QK^T + pi-permuted V, eager bf16 pack, per-kc sched_barrier
// pressure clamp (round-13 verified; round-15 native-cvt improvements).

__global__ __launch_bounds__(512, 2)
void k_attn(const short* __restrict__ qkv, unsigned short* __restrict__ O) {
  __shared__ short Kl[256 * 64];
  __shared__ short Vt[64 * 256];

  const int tid = threadIdx.x, l = tid & 63, w = tid >> 6;
  const int g = (l >> 4) & 3;
  const int bh = blockIdx.x;
  const int bp = bh >> 3, h = bh & 7;
  const size_t tokbase = (size_t)bp * 256 * 1536;
  const int qoff = h * 64, koff = 512 + h * 64, voff = 1024 + h * 64;

#pragma unroll
  for (int c = 0; c < 4; ++c) {
    int ch = tid + c * 512;
    int row = ch >> 3, s = ch & 7;
    int sg = s ^ (row & 7);
    gload_lds16(qkv + tokbase + (size_t)row * 1536 + koff + sg * 8, &Kl[ch * 8]);
  }
#pragma unroll
  for (int c = 0; c < 4; ++c) {
    int ch = tid + c * 512;
    int row = ch >> 3, d0 = (ch & 7) * 8;
    short8 v = *(const short8*)(qkv + tokbase + (size_t)row * 1536 + voff + d0);
    int kc = row >> 5, u = row & 31;
    int gg = (u >> 2) & 3;
    int off = ((u & 16) ? 4 : 0) + (u & 3);
#pragma unroll
    for (int j = 0; j < 8; ++j) {
      int d = d0 + j;
      int sl = (kc * 4 + gg) ^ (d & 15);
      Vt[d * 256 + sl * 8 + off] = v[j];
    }
  }
  __syncthreads();

  const float CEXP = 0.125f * 1.44269504f;

#pragma unroll 1
  for (int it = 0; it < 2; ++it) {
    const int q0 = w * 32 + it * 16;
    bf16x8 qa[2];
#pragma unroll
    for (int dc = 0; dc < 2; ++dc)
      qa[dc] = *(const bf16x8*)(qkv + tokbase + (size_t)(q0 + (l & 15)) * 1536 + qoff +
                                dc * 32 + (l >> 4) * 8);
    f32x4 s[16];
#pragma unroll
    for (int kt = 0; kt < 16; kt++) s[kt] = (f32x4){0.f, 0.f, 0.f, 0.f};
#pragma unroll
    for (int dc = 0; dc < 2; ++dc) {
#pragma unroll
      for (int kt = 0; kt < 16; ++kt) {
        int kcol = kt * 16 + (l & 15);
        int sl = (dc * 4 + (l >> 4)) ^ (kcol & 7);
        bf16x8 kb = *(const bf16x8*)&Kl[kcol * 64 + sl * 8];
        s[kt] = __builtin_amdgcn_mfma_f32_16x16x32_bf16(kb, qa[dc], s[kt], 0, 0, 0);
      }
    }
    float mx = s[0][0];
#pragma unroll
    for (int kt = 0; kt < 16; kt++)
#pragma unroll
      for (int r = 0; r < 4; r++) mx = fmaxf(mx, s[kt][r]);
    mx = fmaxf(mx, __shfl_xor(mx, 16, 64));
    mx = fmaxf(mx, __shfl_xor(mx, 32, 64));

    u32x4 pa[8];
    float sum = 0.f;
#pragma unroll
    for (int kc = 0; kc < 8; ++kc) {
      float p0 = exp2f((s[2 * kc][0] - mx) * CEXP);
      float p1 = exp2f((s[2 * kc][1] - mx) * CEXP);
      float p2 = exp2f((s[2 * kc][2] - mx) * CEXP);
      float p3 = exp2f((s[2 * kc][3] - mx) * CEXP);
      float p4 = exp2f((s[2 * kc + 1][0] - mx) * CEXP);
      float p5 = exp2f((s[2 * kc + 1][1] - mx) * CEXP);
      float p6 = exp2f((s[2 * kc + 1][2] - mx) * CEXP);
      float p7 = exp2f((s[2 * kc + 1][3] - mx) * CEXP);
      sum += ((p0 + p1) + (p2 + p3)) + ((p4 + p5) + (p6 + p7));
      u32x4 pw;
      pw[0] = (unsigned)f2bf(p0) | ((unsigned)f2bf(p1) << 16);
      pw[1] = (unsigned)f2bf(p2) | ((unsigned)f2bf(p3) << 16);
      pw[2] = (unsigned)f2bf(p4) | ((unsigned)f2bf(p5) << 16);
      pw[3] = (unsigned)f2bf(p6) | ((unsigned)f2bf(p7) << 16);
      pa[kc] = pw;
    }
    sum += __shfl_xor(sum, 16, 64);
    sum += __shfl_xor(sum, 32, 64);
    float rs = 1.0f / sum;

    f32x4 o[4];
#pragma unroll
    for (int dt = 0; dt < 4; dt++) o[dt] = (f32x4){0.f, 0.f, 0.f, 0.f};
#pragma unroll
    for (int kc = 0; kc < 8; ++kc) {
      bf16x8 paf = __builtin_bit_cast(bf16x8, pa[kc]);
#pragma unroll
      for (int dt = 0; dt < 4; ++dt) {
        int d = dt * 16 + (l & 15);
        int sl = (kc * 4 + g) ^ (d & 15);
        bf16x8 vb = *(const bf16x8*)&Vt[d * 256 + sl * 8];
        o[dt] = __builtin_amdgcn_mfma_f32_16x16x32_bf16(paf, vb, o[dt], 0, 0, 0);
      }
      __builtin_amdgcn_sched_barrier(0);
    }
    float rsq[4];
#pragma unroll
    for (int r = 0; r < 4; ++r)
      rsq[r] = __shfl(rs, (l & 48) | (g * 4 + r), 64);
#pragma unroll
    for (int dt = 0; dt < 4; dt++) {
#pragma unroll
      for (int r = 0; r < 4; r++) {
        int qrow = q0 + g * 4 + r;
        int d = dt * 16 + (l & 15);
        O[(size_t)(bp * 256 + qrow) * 512 + h * 64 + d] = f2bf(o[dt][r] * rsq[r]);
      }
    }
  }
}

// ---------------- launch ----------------

extern "C" void kernel_launch(void* const* d_in, const int* in_sizes, int n_in,
                              void* d_out, int out_size, void* d_ws, size_t ws_size,
                              hipStream_t stream) {
  const float* x    = (const float*)d_in[0];
  const float* wqkv = (const float*)d_in[1];
  const float* wout = (const float*)d_in[2];
  const float* bout = (const float*)d_in[3];
  float* out = (float*)d_out;
  char* ws = (char*)d_ws;

  // ws layout (O overlaps Xb, which is dead after GEMM1): total ~134.6 MB
  short* Wot = (short*)(ws);                          //   0.39 MB [384][512]
  short* Xb  = (short*)(ws + 393216);                 //  25.17 MB [32768][384]
  short* Wqt = (short*)(ws + 25559040);               //   1.18 MB [1536][384]
  unsigned short* O = (unsigned short*)(ws + 393216); //  33.55 MB [32768][512]
  short* QKV = (short*)(ws + 33947648);               // 100.66 MB [32768][1536]

  k_cast_x<<<6144, 256, 0, stream>>>(x, Xb, 1572864);
  k_transpose_bf<<<2304, 256, 0, stream>>>(wqkv, Wqt, 384, 1536);
  k_transpose_bf<<<768, 256, 0, stream>>>(wout, Wot, 512, 384);
  // GEMM1: 128x256 tiles -> 1536 blocks (%8==0)
  k_gemm<1, 8><<<1536, 256, 0, stream>>>(Xb, Wqt, (unsigned short*)QKV, nullptr, nullptr,
                                         32768, 1536, 384);
  k_attn<<<1024, 512, 0, stream>>>(QKV, O);
  // GEMM2: 128x128 tiles -> 768 blocks (%8==0)
  k_gemm<0, 4><<<768, 256, 0, stream>>>((const short*)O, Wot, nullptr, out, bout,
                                        32768, 384, 512);
  (void)in_sizes; (void)n_in; (void)out_size; (void)ws_size;
}

// Round 17
// 127.801 us; speedup vs baseline: 1.0428x; 1.0428x over previous
//
#include <hip/hip_runtime.h>
#include <stdint.h>

#define DEVFN __device__ __forceinline__

typedef __attribute__((ext_vector_type(8))) __bf16 bf16x8;
typedef __attribute__((ext_vector_type(8))) short short8;
typedef __attribute__((ext_vector_type(4))) float f32x4;
typedef __attribute__((ext_vector_type(4))) unsigned int u32x4;

// Native scalar cast -> hardware v_cvt_pk_bf16_f32 (RNE). (m240)
DEVFN unsigned short f2bf(float f) {
  return __builtin_bit_cast(unsigned short, (__bf16)f);
}

// global -> LDS direct copy, 16B per lane. Dest must be linear in lane order.
DEVFN void gload_lds16(const void* g, void* l) {
  __builtin_amdgcn_global_load_lds(
      (const __attribute__((address_space(1))) void*)(uintptr_t)g,
      (__attribute__((address_space(3))) void*)(uint32_t)(uintptr_t)l,
      16, 0, 0);
}

// ---------------- prep ----------------

// w[R][C] (f32) -> wt[C][R] (bf16)
__global__ void k_transpose_bf(const float* __restrict__ w, short* __restrict__ wt, int R, int C) {
  int i = blockIdx.x * blockDim.x + threadIdx.x;
  if (i >= R * C) return;
  int c = i / R, r = i - c * R;
  wt[i] = (short)f2bf(w[(size_t)r * C + c]);
}

// ---------------- GEMM1 (fused f32->bf16 A-cast): QKV = X * Wqt^T ----------
// Measured best structure (r15 wall ~64us incl. cast saving): 128x256 tile,
// BK=32, A reg-staged f32->cvt_pk->ds_write, B gload_lds, 3-buffer pipeline,
// T1+T2 swizzles, counted vmcnt.

#define LOADA(A0, A1, A2, A3, T)                                             \
  do {                                                                       \
    const float* bA = X + (size_t)(m0 + rowA) * 384 + (T) * 32 + slA * 8;    \
    A0 = *(const f32x4*)bA;                                                  \
    A1 = *(const f32x4*)(bA + 4);                                            \
    A2 = *(const f32x4*)(bA + 64 * 384);                                     \
    A3 = *(const f32x4*)(bA + 64 * 384 + 4);                                 \
  } while (0)

#define WRITEA(BUF, A0, A1, A2, A3)                                          \
  do {                                                                       \
    u32x4 w0_;                                                               \
    w0_[0] = (unsigned)f2bf(A0[0]) | ((unsigned)f2bf(A0[1]) << 16);          \
    w0_[1] = (unsigned)f2bf(A0[2]) | ((unsigned)f2bf(A0[3]) << 16);          \
    w0_[2] = (unsigned)f2bf(A1[0]) | ((unsigned)f2bf(A1[1]) << 16);          \
    w0_[3] = (unsigned)f2bf(A1[2]) | ((unsigned)f2bf(A1[3]) << 16);          \
    *(u32x4*)&As[BUF][tid * 8] = w0_;                                        \
    u32x4 w1_;                                                               \
    w1_[0] = (unsigned)f2bf(A2[0]) | ((unsigned)f2bf(A2[1]) << 16);          \
    w1_[1] = (unsigned)f2bf(A2[2]) | ((unsigned)f2bf(A2[3]) << 16);          \
    w1_[2] = (unsigned)f2bf(A3[0]) | ((unsigned)f2bf(A3[1]) << 16);          \
    w1_[3] = (unsigned)f2bf(A3[2]) | ((unsigned)f2bf(A3[3]) << 16);          \
    *(u32x4*)&As[BUF][(tid + 256) * 8] = w1_;                                \
  } while (0)

#define STEP_MAIN(T, C0, C1, C2, C3, N0, N1, N2, N3)                         \
  do {                                                                       \
    asm volatile("s_waitcnt vmcnt(4) lgkmcnt(0)" ::: "memory");              \
    __builtin_amdgcn_sched_barrier(0);                                       \
    __builtin_amdgcn_s_barrier();                                            \
    __builtin_amdgcn_sched_barrier(0);                                       \
    LOADA(N0, N1, N2, N3, (T) + 2);                                          \
    stageB(((T) + 2) % 3, (T) + 2);                                          \
    WRITEA(((T) + 1) % 3, C0, C1, C2, C3);                                   \
    compute((T) % 3);                                                        \
  } while (0)

__global__ __launch_bounds__(256, 2)
void k_gemm1(const float* __restrict__ X, const short* __restrict__ Bt,
             unsigned short* __restrict__ Cb) {
  __shared__ short As[3][128 * 32];
  __shared__ short Bs[3][256 * 32];
  const int tid = threadIdx.x, l = tid & 63, w = tid >> 6;
  const int nwg = gridDim.x, cpx = nwg >> 3;
  const int bid = (blockIdx.x & 7) * cpx + (blockIdx.x >> 3);
  const int mt = bid / 6, nt = bid % 6;
  const int m0 = mt << 7, n0 = nt * 256;
  const int wm = (w >> 1) << 6, wn = (w & 1) * 128;
  const int rowA = tid >> 2;
  const int slA = (tid & 3) ^ ((rowA >> 1) & 3);

  f32x4 acc[4][8];
#pragma unroll
  for (int i = 0; i < 4; i++)
#pragma unroll
    for (int j = 0; j < 8; j++) acc[i][j] = (f32x4){0.f, 0.f, 0.f, 0.f};

  auto stageB = [&](int buf, int t) {
#pragma unroll
    for (int c = 0; c < 4; ++c) {
      int ch = tid + c * 256;
      int row = ch >> 2;
      int sl = (ch & 3) ^ ((row >> 1) & 3);
      gload_lds16(Bt + (size_t)(n0 + row) * 384 + t * 32 + sl * 8, &Bs[buf][ch * 8]);
    }
  };
  const int sp8 = (((l >> 4) ^ ((l >> 1) & 3)) << 3);
  auto compute = [&](int buf) {
    bf16x8 af[4], bfr[8];
#pragma unroll
    for (int i = 0; i < 4; i++)
      af[i] = *(const bf16x8*)&As[buf][(wm + i * 16 + (l & 15)) * 32 + sp8];
#pragma unroll
    for (int j = 0; j < 8; j++)
      bfr[j] = *(const bf16x8*)&Bs[buf][(wn + j * 16 + (l & 15)) * 32 + sp8];
#pragma unroll
    for (int i = 0; i < 4; i++)
#pragma unroll
      for (int j = 0; j < 8; j++)
        acc[i][j] = __builtin_amdgcn_mfma_f32_16x16x32_bf16(af[i], bfr[j], acc[i][j], 0, 0, 0);
  };

  f32x4 a0_, a1_, a2_, a3_, b0_, b1_, b2_, b3_;
  LOADA(a0_, a1_, a2_, a3_, 0);
  LOADA(b0_, b1_, b2_, b3_, 1);
  stageB(0, 0);
  stageB(1, 1);
  asm volatile("s_waitcnt vmcnt(12)" ::: "memory");  // drain A0
  WRITEA(0, a0_, a1_, a2_, a3_);

#pragma unroll 1
  for (int tp = 0; tp < 10; tp += 2) {
    STEP_MAIN(tp,     b0_, b1_, b2_, b3_, a0_, a1_, a2_, a3_);
    STEP_MAIN(tp + 1, a0_, a1_, a2_, a3_, b0_, b1_, b2_, b3_);
  }
  asm volatile("s_waitcnt vmcnt(4) lgkmcnt(0)" ::: "memory");
  __builtin_amdgcn_sched_barrier(0);
  __builtin_amdgcn_s_barrier();
  __builtin_amdgcn_sched_barrier(0);
  WRITEA(2, b0_, b1_, b2_, b3_);
  compute(1);
  asm volatile("s_waitcnt vmcnt(0) lgkmcnt(0)" ::: "memory");
  __builtin_amdgcn_sched_barrier(0);
  __builtin_amdgcn_s_barrier();
  __builtin_amdgcn_sched_barrier(0);
  compute(2);

#pragma unroll
  for (int i = 0; i < 4; i++) {
    int mrow = m0 + wm + i * 16 + ((l >> 4) << 2);
#pragma unroll
    for (int j = 0; j < 8; j++) {
      int ncol = n0 + wn + j * 16 + (l & 15);
#pragma unroll
      for (int r = 0; r < 4; r++)
        Cb[(size_t)(mrow + r) * 1536 + ncol] = f2bf(acc[i][j][r]);
    }
  }
}

// ---------------- generic GEMM (GEMM2): C = A * Bt^T + bias ----------------

template <int BF16_OUT, int NB>
__global__ __launch_bounds__(256, NB == 8 ? 2 : 3)
void k_gemm(const short* __restrict__ A, const short* __restrict__ Bt,
            unsigned short* __restrict__ Cb, float* __restrict__ Cf,
            const float* __restrict__ bias, int M, int N, int K) {
  constexpr int BN = NB * 32;
  constexpr int BCH = NB / 2;
  __shared__ short As[3][128 * 32];
  __shared__ short Bs[3][BN * 32];
  const int tid = threadIdx.x;
  const int l = tid & 63, w = tid >> 6;
  const int ntile = N / BN;
  const int nwg = gridDim.x, cpx = nwg >> 3;
  const int bid = (blockIdx.x & 7) * cpx + (blockIdx.x >> 3);
  const int mt = bid / ntile, nt = bid % ntile;
  const int m0 = mt << 7, n0 = nt * BN;
  const int wm = (w >> 1) << 6, wn = (w & 1) * (NB * 16);

  f32x4 acc[4][NB];
#pragma unroll
  for (int i = 0; i < 4; i++)
#pragma unroll
    for (int j = 0; j < NB; j++) acc[i][j] = (f32x4){0.f, 0.f, 0.f, 0.f};

  const int nsteps = K >> 5;

  auto stage = [&](int buf, int t) {
#pragma unroll
    for (int c = 0; c < 2; ++c) {
      int ch = tid + c * 256;
      int row = ch >> 2;
      int sl = (ch & 3) ^ ((row >> 1) & 3);
      gload_lds16(A + (size_t)(m0 + row) * K + t * 32 + sl * 8, &As[buf][ch * 8]);
    }
#pragma unroll
    for (int c = 0; c < BCH; ++c) {
      int ch = tid + c * 256;
      int row = ch >> 2;
      int sl = (ch & 3) ^ ((row >> 1) & 3);
      gload_lds16(Bt + (size_t)(n0 + row) * K + t * 32 + sl * 8, &Bs[buf][ch * 8]);
    }
  };
  const int sp8 = (((l >> 4) ^ ((l >> 1) & 3)) << 3);
  auto compute = [&](int buf) {
    bf16x8 af[4], bfr[NB];
#pragma unroll
    for (int i = 0; i < 4; i++)
      af[i] = *(const bf16x8*)&As[buf][(wm + i * 16 + (l & 15)) * 32 + sp8];
#pragma unroll
    for (int j = 0; j < NB; j++)
      bfr[j] = *(const bf16x8*)&Bs[buf][(wn + j * 16 + (l & 15)) * 32 + sp8];
#pragma unroll
    for (int i = 0; i < 4; i++)
#pragma unroll
      for (int j = 0; j < NB; j++)
        acc[i][j] = __builtin_amdgcn_mfma_f32_16x16x32_bf16(af[i], bfr[j], acc[i][j], 0, 0, 0);
  };

  stage(0, 0);
  stage(1, 1);
#pragma unroll 1
  for (int t = 0; t < nsteps; ++t) {
    if (t + 1 < nsteps) {
      if constexpr (NB == 8)
        asm volatile("s_waitcnt vmcnt(6)" ::: "memory");
      else
        asm volatile("s_waitcnt vmcnt(4)" ::: "memory");
    } else {
      asm volatile("s_waitcnt vmcnt(0)" ::: "memory");
    }
    __builtin_amdgcn_sched_barrier(0);
    __builtin_amdgcn_s_barrier();
    __builtin_amdgcn_sched_barrier(0);
    if (t + 2 < nsteps) stage((t + 2) % 3, t + 2);
    compute(t % 3);
  }

#pragma unroll
  for (int i = 0; i < 4; i++) {
    int mrow = m0 + wm + i * 16 + ((l >> 4) << 2);
#pragma unroll
    for (int j = 0; j < NB; j++) {
      int ncol = n0 + wn + j * 16 + (l & 15);
#pragma unroll
      for (int r = 0; r < 4; r++) {
        if (BF16_OUT) {
          Cb[(size_t)(mrow + r) * N + ncol] = f2bf(acc[i][j][r]);
        } else {
          Cf[(size_t)(mrow + r) * N + ncol] = acc[i][j][r] + bias[ncol];
        }
      }
    }
  }
}

// ---------------- fused attention per (bp, head) ----------------
// Swapped QK^T + pi-permuted V, eager bf16 pack, per-kc sched_barrier
// pressure clamp. NEW (T5, m191): setprio(1) around MFMA clusters — attn's
// 8 waves are barrier-free after staging (role-diverse), the regime where
// setprio pays (+4-7% attn; null on lockstep GEMM so not applied there).

__global__ __launch_bounds__(512, 2)
void k_attn(const short* __restrict__ qkv, unsigned short* __restrict__ O) {
  __shared__ short Kl[256 * 64];
  __shared__ short Vt[64 * 256];

  const int tid = threadIdx.x, l = tid & 63, w = tid >> 6;
  const int g = (l >> 4) & 3;
  const int bh = blockIdx.x;
  const int bp = bh >> 3, h = bh & 7;
  const size_t tokbase = (size_t)bp * 256 * 1536;
  const int qoff = h * 64, koff = 512 + h * 64, voff = 1024 + h * 64;

#pragma unroll
  for (int c = 0; c < 4; ++c) {
    int ch = tid + c * 512;
    int row = ch >> 3, s = ch & 7;
    int sg = s ^ (row & 7);
    gload_lds16(qkv + tokbase + (size_t)row * 1536 + koff + sg * 8, &Kl[ch * 8]);
  }
#pragma unroll
  for (int c = 0; c < 4; ++c) {
    int ch = tid + c * 512;
    int row = ch >> 3, d0 = (ch & 7) * 8;
    short8 v = *(const short8*)(qkv + tokbase + (size_t)row * 1536 + voff + d0);
    int kc = row >> 5, u = row & 31;
    int gg = (u >> 2) & 3;
    int off = ((u & 16) ? 4 : 0) + (u & 3);
#pragma unroll
    for (int j = 0; j < 8; ++j) {
      int d = d0 + j;
      int sl = (kc * 4 + gg) ^ (d & 15);
      Vt[d * 256 + sl * 8 + off] = v[j];
    }
  }
  __syncthreads();

  const float CEXP = 0.125f * 1.44269504f;

#pragma unroll 1
  for (int it = 0; it < 2; ++it) {
    const int q0 = w * 32 + it * 16;
    bf16x8 qa[2];
#pragma unroll
    for (int dc = 0; dc < 2; ++dc)
      qa[dc] = *(const bf16x8*)(qkv + tokbase + (size_t)(q0 + (l & 15)) * 1536 + qoff +
                                dc * 32 + (l >> 4) * 8);
    f32x4 s[16];
#pragma unroll
    for (int kt = 0; kt < 16; kt++) s[kt] = (f32x4){0.f, 0.f, 0.f, 0.f};
    __builtin_amdgcn_s_setprio(1);
#pragma unroll
    for (int dc = 0; dc < 2; ++dc) {
#pragma unroll
      for (int kt = 0; kt < 16; ++kt) {
        int kcol = kt * 16 + (l & 15);
        int sl = (dc * 4 + (l >> 4)) ^ (kcol & 7);
        bf16x8 kb = *(const bf16x8*)&Kl[kcol * 64 + sl * 8];
        s[kt] = __builtin_amdgcn_mfma_f32_16x16x32_bf16(kb, qa[dc], s[kt], 0, 0, 0);
      }
    }
    __builtin_amdgcn_s_setprio(0);
    float mx = s[0][0];
#pragma unroll
    for (int kt = 0; kt < 16; kt++)
#pragma unroll
      for (int r = 0; r < 4; r++) mx = fmaxf(mx, s[kt][r]);
    mx = fmaxf(mx, __shfl_xor(mx, 16, 64));
    mx = fmaxf(mx, __shfl_xor(mx, 32, 64));

    u32x4 pa[8];
    float sum = 0.f;
#pragma unroll
    for (int kc = 0; kc < 8; ++kc) {
      float p0 = exp2f((s[2 * kc][0] - mx) * CEXP);
      float p1 = exp2f((s[2 * kc][1] - mx) * CEXP);
      float p2 = exp2f((s[2 * kc][2] - mx) * CEXP);
      float p3 = exp2f((s[2 * kc][3] - mx) * CEXP);
      float p4 = exp2f((s[2 * kc + 1][0] - mx) * CEXP);
      float p5 = exp2f((s[2 * kc + 1][1] - mx) * CEXP);
      float p6 = exp2f((s[2 * kc + 1][2] - mx) * CEXP);
      float p7 = exp2f((s[2 * kc + 1][3] - mx) * CEXP);
      sum += ((p0 + p1) + (p2 + p3)) + ((p4 + p5) + (p6 + p7));
      u32x4 pw;
      pw[0] = (unsigned)f2bf(p0) | ((unsigned)f2bf(p1) << 16);
      pw[1] = (unsigned)f2bf(p2) | ((unsigned)f2bf(p3) << 16);
      pw[2] = (unsigned)f2bf(p4) | ((unsigned)f2bf(p5) << 16);
      pw[3] = (unsigned)f2bf(p6) | ((unsigned)f2bf(p7) << 16);
      pa[kc] = pw;
    }
    sum += __shfl_xor(sum, 16, 64);
    sum += __shfl_xor(sum, 32, 64);
    float rs = 1.0f / sum;

    f32x4 o[4];
#pragma unroll
    for (int dt = 0; dt < 4; dt++) o[dt] = (f32x4){0.f, 0.f, 0.f, 0.f};
#pragma unroll
    for (int kc = 0; kc < 8; ++kc) {
      bf16x8 paf = __builtin_bit_cast(bf16x8, pa[kc]);
      __builtin_amdgcn_s_setprio(1);
#pragma unroll
      for (int dt = 0; dt < 4; ++dt) {
        int d = dt * 16 + (l & 15);
        int sl = (kc * 4 + g) ^ (d & 15);
        bf16x8 vb = *(const bf16x8*)&Vt[d * 256 + sl * 8];
        o[dt] = __builtin_amdgcn_mfma_f32_16x16x32_bf16(paf, vb, o[dt], 0, 0, 0);
      }
      __builtin_amdgcn_s_setprio(0);
      __builtin_amdgcn_sched_barrier(0);
    }
    float rsq[4];
#pragma unroll
    for (int r = 0; r < 4; ++r)
      rsq[r] = __shfl(rs, (l & 48) | (g * 4 + r), 64);
#pragma unroll
    for (int dt = 0; dt < 4; dt++) {
#pragma unroll
      for (int r = 0; r < 4; r++) {
        int qrow = q0 + g * 4 + r;
        int d = dt * 16 + (l & 15);
        O[(size_t)(bp * 256 + qrow) * 512 + h * 64 + d] = f2bf(o[dt][r] * rsq[r]);
      }
    }
  }
}

// ---------------- launch ----------------

extern "C" void kernel_launch(void* const* d_in, const int* in_sizes, int n_in,
                              void* d_out, int out_size, void* d_ws, size_t ws_size,
                              hipStream_t stream) {
  const float* x    = (const float*)d_in[0];
  const float* wqkv = (const float*)d_in[1];
  const float* wout = (const float*)d_in[2];
  const float* bout = (const float*)d_in[3];
  float* out = (float*)d_out;
  char* ws = (char*)d_ws;

  // ws layout: Xb slot retired (cast fused into k_gemm1).
  short* Wot = (short*)(ws);                          //   0.39 MB [384][512]
  short* Wqt = (short*)(ws + 25559040);               //   1.18 MB [1536][384]
  unsigned short* O = (unsigned short*)(ws + 393216); //  33.55 MB [32768][512]
  short* QKV = (short*)(ws + 33947648);               // 100.66 MB [32768][1536]

  k_transpose_bf<<<2304, 256, 0, stream>>>(wqkv, Wqt, 384, 1536);
  k_transpose_bf<<<768, 256, 0, stream>>>(wout, Wot, 512, 384);
  // GEMM1 (fused cast): 128x256 tiles -> 1536 blocks (%8==0)
  k_gemm1<<<1536, 256, 0, stream>>>(x, Wqt, (unsigned short*)QKV);
  k_attn<<<1024, 512, 0, stream>>>(QKV, O);
  // GEMM2: 128x128 tiles -> 768 blocks (%8==0)
  k_gemm<0, 4><<<768, 256, 0, stream>>>((const short*)O, Wot, nullptr, out, bout,
                                        32768, 384, 512);
  (void)in_sizes; (void)n_in; (void)out_size; (void)ws_size;
}

// Round 18
// 124.798 us; speedup vs baseline: 1.0679x; 1.0241x over previous
//
#include <hip/hip_runtime.h>
#include <stdint.h>

#define DEVFN __device__ __forceinline__

typedef __attribute__((ext_vector_type(8))) __bf16 bf16x8;
typedef __attribute__((ext_vector_type(8))) short short8;
typedef __attribute__((ext_vector_type(4))) float f32x4;
typedef __attribute__((ext_vector_type(4))) unsigned int u32x4;

// Native scalar cast -> hardware v_cvt_pk_bf16_f32 (RNE). (m240)
DEVFN unsigned short f2bf(float f) {
  return __builtin_bit_cast(unsigned short, (__bf16)f);
}

// global -> LDS direct copy, 16B per lane. Dest must be linear in lane order.
DEVFN void gload_lds16(const void* g, void* l) {
  __builtin_amdgcn_global_load_lds(
      (const __attribute__((address_space(1))) void*)(uintptr_t)g,
      (__attribute__((address_space(3))) void*)(uint32_t)(uintptr_t)l,
      16, 0, 0);
}

// ---------------- prep (merged: both weight transposes in one launch) ------

__global__ void k_prep(const float* __restrict__ wqkv, const float* __restrict__ wout,
                       short* __restrict__ Wqt, short* __restrict__ Wot) {
  int i = blockIdx.x * blockDim.x + threadIdx.x;
  if (i < 589824) {                       // Wqt[c][r] = wqkv[r][c], 384x1536
    int c = i / 384, r = i - c * 384;
    Wqt[i] = (short)f2bf(wqkv[(size_t)r * 1536 + c]);
  } else {
    int j = i - 589824;                   // Wot[c][r] = wout[r][c], 512x384
    if (j < 196608) {
      int c = j / 512, r = j - c * 512;
      Wot[j] = (short)f2bf(wout[(size_t)r * 384 + c]);
    }
  }
}

// ---------------- GEMM1 (fused f32->bf16 A-cast): QKV = X * Wqt^T ----------
// 128x256 tile, BK=32, A reg-staged f32->cvt_pk->ds_write, B gload_lds,
// 3-buffer pipeline, T1+T2 swizzles, counted vmcnt. (Measured best r15/r17.)

#define LOADA(A0, A1, A2, A3, T)                                             \
  do {                                                                       \
    const float* bA = X + (size_t)(m0 + rowA) * 384 + (T) * 32 + slA * 8;    \
    A0 = *(const f32x4*)bA;                                                  \
    A1 = *(const f32x4*)(bA + 4);                                            \
    A2 = *(const f32x4*)(bA + 64 * 384);                                     \
    A3 = *(const f32x4*)(bA + 64 * 384 + 4);                                 \
  } while (0)

#define WRITEA(BUF, A0, A1, A2, A3)                                          \
  do {                                                                       \
    u32x4 w0_;                                                               \
    w0_[0] = (unsigned)f2bf(A0[0]) | ((unsigned)f2bf(A0[1]) << 16);          \
    w0_[1] = (unsigned)f2bf(A0[2]) | ((unsigned)f2bf(A0[3]) << 16);          \
    w0_[2] = (unsigned)f2bf(A1[0]) | ((unsigned)f2bf(A1[1]) << 16);          \
    w0_[3] = (unsigned)f2bf(A1[2]) | ((unsigned)f2bf(A1[3]) << 16);          \
    *(u32x4*)&As[BUF][tid * 8] = w0_;                                        \
    u32x4 w1_;                                                               \
    w1_[0] = (unsigned)f2bf(A2[0]) | ((unsigned)f2bf(A2[1]) << 16);          \
    w1_[1] = (unsigned)f2bf(A2[2]) | ((unsigned)f2bf(A2[3]) << 16);          \
    w1_[2] = (unsigned)f2bf(A3[0]) | ((unsigned)f2bf(A3[1]) << 16);          \
    w1_[3] = (unsigned)f2bf(A3[2]) | ((unsigned)f2bf(A3[3]) << 16);          \
    *(u32x4*)&As[BUF][(tid + 256) * 8] = w1_;                                \
  } while (0)

#define STEP_MAIN(T, C0, C1, C2, C3, N0, N1, N2, N3)                         \
  do {                                                                       \
    asm volatile("s_waitcnt vmcnt(4) lgkmcnt(0)" ::: "memory");              \
    __builtin_amdgcn_sched_barrier(0);                                       \
    __builtin_amdgcn_s_barrier();                                            \
    __builtin_amdgcn_sched_barrier(0);                                       \
    LOADA(N0, N1, N2, N3, (T) + 2);                                          \
    stageB(((T) + 2) % 3, (T) + 2);                                          \
    WRITEA(((T) + 1) % 3, C0, C1, C2, C3);                                   \
    compute((T) % 3);                                                        \
  } while (0)

__global__ __launch_bounds__(256, 2)
void k_gemm1(const float* __restrict__ X, const short* __restrict__ Bt,
             unsigned short* __restrict__ Cb) {
  __shared__ short As[3][128 * 32];
  __shared__ short Bs[3][256 * 32];
  const int tid = threadIdx.x, l = tid & 63, w = tid >> 6;
  const int nwg = gridDim.x, cpx = nwg >> 3;
  const int bid = (blockIdx.x & 7) * cpx + (blockIdx.x >> 3);
  const int mt = bid / 6, nt = bid % 6;
  const int m0 = mt << 7, n0 = nt * 256;
  const int wm = (w >> 1) << 6, wn = (w & 1) * 128;
  const int rowA = tid >> 2;
  const int slA = (tid & 3) ^ ((rowA >> 1) & 3);

  f32x4 acc[4][8];
#pragma unroll
  for (int i = 0; i < 4; i++)
#pragma unroll
    for (int j = 0; j < 8; j++) acc[i][j] = (f32x4){0.f, 0.f, 0.f, 0.f};

  auto stageB = [&](int buf, int t) {
#pragma unroll
    for (int c = 0; c < 4; ++c) {
      int ch = tid + c * 256;
      int row = ch >> 2;
      int sl = (ch & 3) ^ ((row >> 1) & 3);
      gload_lds16(Bt + (size_t)(n0 + row) * 384 + t * 32 + sl * 8, &Bs[buf][ch * 8]);
    }
  };
  const int sp8 = (((l >> 4) ^ ((l >> 1) & 3)) << 3);
  auto compute = [&](int buf) {
    bf16x8 af[4], bfr[8];
#pragma unroll
    for (int i = 0; i < 4; i++)
      af[i] = *(const bf16x8*)&As[buf][(wm + i * 16 + (l & 15)) * 32 + sp8];
#pragma unroll
    for (int j = 0; j < 8; j++)
      bfr[j] = *(const bf16x8*)&Bs[buf][(wn + j * 16 + (l & 15)) * 32 + sp8];
#pragma unroll
    for (int i = 0; i < 4; i++)
#pragma unroll
      for (int j = 0; j < 8; j++)
        acc[i][j] = __builtin_amdgcn_mfma_f32_16x16x32_bf16(af[i], bfr[j], acc[i][j], 0, 0, 0);
  };

  f32x4 a0_, a1_, a2_, a3_, b0_, b1_, b2_, b3_;
  LOADA(a0_, a1_, a2_, a3_, 0);
  LOADA(b0_, b1_, b2_, b3_, 1);
  stageB(0, 0);
  stageB(1, 1);
  asm volatile("s_waitcnt vmcnt(12)" ::: "memory");  // drain A0
  WRITEA(0, a0_, a1_, a2_, a3_);

#pragma unroll 1
  for (int tp = 0; tp < 10; tp += 2) {
    STEP_MAIN(tp,     b0_, b1_, b2_, b3_, a0_, a1_, a2_, a3_);
    STEP_MAIN(tp + 1, a0_, a1_, a2_, a3_, b0_, b1_, b2_, b3_);
  }
  asm volatile("s_waitcnt vmcnt(4) lgkmcnt(0)" ::: "memory");
  __builtin_amdgcn_sched_barrier(0);
  __builtin_amdgcn_s_barrier();
  __builtin_amdgcn_sched_barrier(0);
  WRITEA(2, b0_, b1_, b2_, b3_);
  compute(1);
  asm volatile("s_waitcnt vmcnt(0) lgkmcnt(0)" ::: "memory");
  __builtin_amdgcn_sched_barrier(0);
  __builtin_amdgcn_s_barrier();
  __builtin_amdgcn_sched_barrier(0);
  compute(2);

#pragma unroll
  for (int i = 0; i < 4; i++) {
    int mrow = m0 + wm + i * 16 + ((l >> 4) << 2);
#pragma unroll
    for (int j = 0; j < 8; j++) {
      int ncol = n0 + wn + j * 16 + (l & 15);
#pragma unroll
      for (int r = 0; r < 4; r++)
        Cb[(size_t)(mrow + r) * 1536 + ncol] = f2bf(acc[i][j][r]);
    }
  }
}

// ---------------- GEMM2: out = O * Wot^T + bias ----------------------------
// NEW geometry: 256x128 tile, 512 threads (8 waves, 4M x 2N of 64x64 each).
// Same proven template family (3-buffer, counted vmcnt, T1+T2 swizzles) but
// 2 blocks/CU x 8 waves = 16 waves/CU (was 12) for more TLP over the
// 2-phase stalls. Stage = 3 uniform loads/thread (A:2, B:1) -> vmcnt(3).
// M=32768, N=384, K=512 hardcoded. Grid 128*3 = 384 (%8==0).

__global__ __launch_bounds__(512, 2)
void k_gemm2(const short* __restrict__ A, const short* __restrict__ Bt,
             float* __restrict__ Cf, const float* __restrict__ bias) {
  __shared__ short As[3][256 * 32];
  __shared__ short Bs[3][128 * 32];
  const int tid = threadIdx.x;
  const int l = tid & 63, w = tid >> 6;
  const int nwg = gridDim.x, cpx = nwg >> 3;
  const int bid = (blockIdx.x & 7) * cpx + (blockIdx.x >> 3);
  const int mt = bid / 3, nt = bid % 3;
  const int m0 = mt << 8, n0 = nt << 7;
  const int wm = (w >> 1) << 6, wn = (w & 1) << 6;

  f32x4 acc[4][4];
#pragma unroll
  for (int i = 0; i < 4; i++)
#pragma unroll
    for (int j = 0; j < 4; j++) acc[i][j] = (f32x4){0.f, 0.f, 0.f, 0.f};

  const int nsteps = 16;  // K=512 / 32

  auto stage = [&](int buf, int t) {
#pragma unroll
    for (int c = 0; c < 2; ++c) {
      int ch = tid + c * 512;           // 1024 chunks: 256 rows x 4 slots
      int row = ch >> 2;
      int sl = (ch & 3) ^ ((row >> 1) & 3);
      gload_lds16(A + (size_t)(m0 + row) * 512 + t * 32 + sl * 8, &As[buf][ch * 8]);
    }
    {
      int ch = tid;                     // 512 chunks: 128 rows x 4 slots
      int row = ch >> 2;
      int sl = (ch & 3) ^ ((row >> 1) & 3);
      gload_lds16(Bt + (size_t)(n0 + row) * 512 + t * 32 + sl * 8, &Bs[buf][ch * 8]);
    }
  };
  const int sp8 = (((l >> 4) ^ ((l >> 1) & 3)) << 3);
  auto compute = [&](int buf) {
    bf16x8 af[4], bfr[4];
#pragma unroll
    for (int i = 0; i < 4; i++)
      af[i] = *(const bf16x8*)&As[buf][(wm + i * 16 + (l & 15)) * 32 + sp8];
#pragma unroll
    for (int j = 0; j < 4; j++)
      bfr[j] = *(const bf16x8*)&Bs[buf][(wn + j * 16 + (l & 15)) * 32 + sp8];
#pragma unroll
    for (int i = 0; i < 4; i++)
#pragma unroll
      for (int j = 0; j < 4; j++)
        acc[i][j] = __builtin_amdgcn_mfma_f32_16x16x32_bf16(af[i], bfr[j], acc[i][j], 0, 0, 0);
  };

  stage(0, 0);
  stage(1, 1);
#pragma unroll 1
  for (int t = 0; t < nsteps; ++t) {
    if (t + 1 < nsteps) {
      asm volatile("s_waitcnt vmcnt(3)" ::: "memory");  // drain my stage-t (3 loads)
    } else {
      asm volatile("s_waitcnt vmcnt(0)" ::: "memory");
    }
    __builtin_amdgcn_sched_barrier(0);
    __builtin_amdgcn_s_barrier();
    __builtin_amdgcn_sched_barrier(0);
    if (t + 2 < nsteps) stage((t + 2) % 3, t + 2);
    compute(t % 3);
  }

#pragma unroll
  for (int i = 0; i < 4; i++) {
    int mrow = m0 + wm + i * 16 + ((l >> 4) << 2);
#pragma unroll
    for (int j = 0; j < 4; j++) {
      int ncol = n0 + wn + j * 16 + (l & 15);
#pragma unroll
      for (int r = 0; r < 4; r++)
        Cf[(size_t)(mrow + r) * 384 + ncol] = acc[i][j][r] + bias[ncol];
    }
  }
}

// ---------------- fused attention per (bp, head) ----------------
// Swapped QK^T + pi-permuted V, eager bf16 pack, per-kc sched_barrier
// pressure clamp, T5 setprio around MFMA clusters. (r17 verified)

__global__ __launch_bounds__(512, 2)
void k_attn(const short* __restrict__ qkv, unsigned short* __restrict__ O) {
  __shared__ short Kl[256 * 64];
  __shared__ short Vt[64 * 256];

  const int tid = threadIdx.x, l = tid & 63, w = tid >> 6;
  const int g = (l >> 4) & 3;
  const int bh = blockIdx.x;
  const int bp = bh >> 3, h = bh & 7;
  const size_t tokbase = (size_t)bp * 256 * 1536;
  const int qoff = h * 64, koff = 512 + h * 64, voff = 1024 + h * 64;

#pragma unroll
  for (int c = 0; c < 4; ++c) {
    int ch = tid + c * 512;
    int row = ch >> 3, s = ch & 7;
    int sg = s ^ (row & 7);
    gload_lds16(qkv + tokbase + (size_t)row * 1536 + koff + sg * 8, &Kl[ch * 8]);
  }
#pragma unroll
  for (int c = 0; c < 4; ++c) {
    int ch = tid + c * 512;
    int row = ch >> 3, d0 = (ch & 7) * 8;
    short8 v = *(const short8*)(qkv + tokbase + (size_t)row * 1536 + voff + d0);
    int kc = row >> 5, u = row & 31;
    int gg = (u >> 2) & 3;
    int off = ((u & 16) ? 4 : 0) + (u & 3);
#pragma unroll
    for (int j = 0; j < 8; ++j) {
      int d = d0 + j;
      int sl = (kc * 4 + gg) ^ (d & 15);
      Vt[d * 256 + sl * 8 + off] = v[j];
    }
  }
  __syncthreads();

  const float CEXP = 0.125f * 1.44269504f;

#pragma unroll 1
  for (int it = 0; it < 2; ++it) {
    const int q0 = w * 32 + it * 16;
    bf16x8 qa[2];
#pragma unroll
    for (int dc = 0; dc < 2; ++dc)
      qa[dc] = *(const bf16x8*)(qkv + tokbase + (size_t)(q0 + (l & 15)) * 1536 + qoff +
                                dc * 32 + (l >> 4) * 8);
    f32x4 s[16];
#pragma unroll
    for (int kt = 0; kt < 16; kt++) s[kt] = (f32x4){0.f, 0.f, 0.f, 0.f};
    __builtin_amdgcn_s_setprio(1);
#pragma unroll
    for (int dc = 0; dc < 2; ++dc) {
#pragma unroll
      for (int kt = 0; kt < 16; ++kt) {
        int kcol = kt * 16 + (l & 15);
        int sl = (dc * 4 + (l >> 4)) ^ (kcol & 7);
        bf16x8 kb = *(const bf16x8*)&Kl[kcol * 64 + sl * 8];
        s[kt] = __builtin_amdgcn_mfma_f32_16x16x32_bf16(kb, qa[dc], s[kt], 0, 0, 0);
      }
    }
    __builtin_amdgcn_s_setprio(0);
    float mx = s[0][0];
#pragma unroll
    for (int kt = 0; kt < 16; kt++)
#pragma unroll
      for (int r = 0; r < 4; r++) mx = fmaxf(mx, s[kt][r]);
    mx = fmaxf(mx, __shfl_xor(mx, 16, 64));
    mx = fmaxf(mx, __shfl_xor(mx, 32, 64));

    u32x4 pa[8];
    float sum = 0.f;
#pragma unroll
    for (int kc = 0; kc < 8; ++kc) {
      float p0 = exp2f((s[2 * kc][0] - mx) * CEXP);
      float p1 = exp2f((s[2 * kc][1] - mx) * CEXP);
      float p2 = exp2f((s[2 * kc][2] - mx) * CEXP);
      float p3 = exp2f((s[2 * kc][3] - mx) * CEXP);
      float p4 = exp2f((s[2 * kc + 1][0] - mx) * CEXP);
      float p5 = exp2f((s[2 * kc + 1][1] - mx) * CEXP);
      float p6 = exp2f((s[2 * kc + 1][2] - mx) * CEXP);
      float p7 = exp2f((s[2 * kc + 1][3] - mx) * CEXP);
      sum += ((p0 + p1) + (p2 + p3)) + ((p4 + p5) + (p6 + p7));
      u32x4 pw;
      pw[0] = (unsigned)f2bf(p0) | ((unsigned)f2bf(p1) << 16);
      pw[1] = (unsigned)f2bf(p2) | ((unsigned)f2bf(p3) << 16);
      pw[2] = (unsigned)f2bf(p4) | ((unsigned)f2bf(p5) << 16);
      pw[3] = (unsigned)f2bf(p6) | ((unsigned)f2bf(p7) << 16);
      pa[kc] = pw;
    }
    sum += __shfl_xor(sum, 16, 64);
    sum += __shfl_xor(sum, 32, 64);
    float rs = 1.0f / sum;

    f32x4 o[4];
#pragma unroll
    for (int dt = 0; dt < 4; dt++) o[dt] = (f32x4){0.f, 0.f, 0.f, 0.f};
#pragma unroll
    for (int kc = 0; kc < 8; ++kc) {
      bf16x8 paf = __builtin_bit_cast(bf16x8, pa[kc]);
      __builtin_amdgcn_s_setprio(1);
#pragma unroll
      for (int dt = 0; dt < 4; ++dt) {
        int d = dt * 16 + (l & 15);
        int sl = (kc * 4 + g) ^ (d & 15);
        bf16x8 vb = *(const bf16x8*)&Vt[d * 256 + sl * 8];
        o[dt] = __builtin_amdgcn_mfma_f32_16x16x32_bf16(paf, vb, o[dt], 0, 0, 0);
      }
      __builtin_amdgcn_s_setprio(0);
      __builtin_amdgcn_sched_barrier(0);
    }
    float rsq[4];
#pragma unroll
    for (int r = 0; r < 4; ++r)
      rsq[r] = __shfl(rs, (l & 48) | (g * 4 + r), 64);
#pragma unroll
    for (int dt = 0; dt < 4; dt++) {
#pragma unroll
      for (int r = 0; r < 4; r++) {
        int qrow = q0 + g * 4 + r;
        int d = dt * 16 + (l & 15);
        O[(size_t)(bp * 256 + qrow) * 512 + h * 64 + d] = f2bf(o[dt][r] * rsq[r]);
      }
    }
  }
}

// ---------------- launch ----------------

extern "C" void kernel_launch(void* const* d_in, const int* in_sizes, int n_in,
                              void* d_out, int out_size, void* d_ws, size_t ws_size,
                              hipStream_t stream) {
  const float* x    = (const float*)d_in[0];
  const float* wqkv = (const float*)d_in[1];
  const float* wout = (const float*)d_in[2];
  const float* bout = (const float*)d_in[3];
  float* out = (float*)d_out;
  char* ws = (char*)d_ws;

  short* Wot = (short*)(ws);                          //   0.39 MB [384][512]
  short* Wqt = (short*)(ws + 25559040);               //   1.18 MB [1536][384]
  unsigned short* O = (unsigned short*)(ws + 393216); //  33.55 MB [32768][512]
  short* QKV = (short*)(ws + 33947648);               // 100.66 MB [32768][1536]

  k_prep<<<3072, 256, 0, stream>>>(wqkv, wout, Wqt, Wot);
  // GEMM1 (fused cast): 128x256 tiles -> 1536 blocks (%8==0)
  k_gemm1<<<1536, 256, 0, stream>>>(x, Wqt, (unsigned short*)QKV);
  k_attn<<<1024, 512, 0, stream>>>(QKV, O);
  // GEMM2: 256x128 tiles -> 384 blocks (%8==0)
  k_gemm2<<<384, 512, 0, stream>>>((const short*)O, Wot, out, bout);
  (void)in_sizes; (void)n_in; (void)out_size; (void)ws_size;
}

// Round 19
// 122.066 us; speedup vs baseline: 1.0918x; 1.0224x over previous
//
#include <hip/hip_runtime.h>
#include <stdint.h>

#define DEVFN __device__ __forceinline__

typedef __attribute__((ext_vector_type(8))) __bf16 bf16x8;
typedef __attribute__((ext_vector_type(8))) short short8;
typedef __attribute__((ext_vector_type(4))) float f32x4;
typedef __attribute__((ext_vector_type(4))) unsigned int u32x4;

// Native scalar cast -> hardware v_cvt_pk_bf16_f32 (RNE). (m240)
DEVFN unsigned short f2bf(float f) {
  return __builtin_bit_cast(unsigned short, (__bf16)f);
}

// global -> LDS direct copy, 16B per lane. Dest must be linear in lane order.
DEVFN void gload_lds16(const void* g, void* l) {
  __builtin_amdgcn_global_load_lds(
      (const __attribute__((address_space(1))) void*)(uintptr_t)g,
      (__attribute__((address_space(3))) void*)(uint32_t)(uintptr_t)l,
      16, 0, 0);
}

// ---------------- prep (merged weight transposes) ----------

__global__ void k_prep(const float* __restrict__ wqkv, const float* __restrict__ wout,
                       short* __restrict__ Wqt, short* __restrict__ Wot) {
  int i = blockIdx.x * blockDim.x + threadIdx.x;
  if (i < 589824) {                       // Wqt[c][r] = wqkv[r][c], 384x1536
    int c = i / 384, r = i - c * 384;
    Wqt[i] = (short)f2bf(wqkv[(size_t)r * 1536 + c]);
  } else {
    int j = i - 589824;                   // Wot[c][r] = wout[r][c], 512x384
    if (j < 196608) {
      int c = j / 512, r = j - c * 512;
      Wot[j] = (short)f2bf(wout[(size_t)r * 384 + c]);
    }
  }
}

// ---------------- GEMM1 (fused f32->bf16 A-cast): QKV = X * Wqt^T ----------
// NEW: 512 threads, 8 waves (2M x 4N of 64x64 each), same 128x256 tile /
// 72KB 3-buffer LDS -> 2 blocks/CU x 8 waves = 16 waves/CU (4/SIMD, was 2).
// gemm1 was the lowest-occupancy kernel left; r18's gemm2 showed the same
// template gains from doubling waves/SIMD (TLP covers the 2-phase stalls).
// Per-thread staging halves: LOADA 2xf32x4, WRITEA 1 chunk, stageB 2 gloads.
// vmcnt FIFO recount: prologue vmcnt(6) drains A0-of-8; steady vmcnt(2)
// drains A(t+1)+B(t) keeping B(t+1); tail 2 -> 0.

#define LOADA(A0, A1, T)                                                     \
  do {                                                                       \
    const float* bA = X + (size_t)(m0 + rowA) * 384 + (T) * 32 + slA * 8;    \
    A0 = *(const f32x4*)bA;                                                  \
    A1 = *(const f32x4*)(bA + 4);                                            \
  } while (0)

#define WRITEA(BUF, A0, A1)                                                  \
  do {                                                                       \
    u32x4 w0_;                                                               \
    w0_[0] = (unsigned)f2bf(A0[0]) | ((unsigned)f2bf(A0[1]) << 16);          \
    w0_[1] = (unsigned)f2bf(A0[2]) | ((unsigned)f2bf(A0[3]) << 16);          \
    w0_[2] = (unsigned)f2bf(A1[0]) | ((unsigned)f2bf(A1[1]) << 16);          \
    w0_[3] = (unsigned)f2bf(A1[2]) | ((unsigned)f2bf(A1[3]) << 16);          \
    *(u32x4*)&As[BUF][tid * 8] = w0_;                                        \
  } while (0)

#define STEP_MAIN(T, C0, C1, N0, N1)                                         \
  do {                                                                       \
    asm volatile("s_waitcnt vmcnt(2) lgkmcnt(0)" ::: "memory");              \
    __builtin_amdgcn_sched_barrier(0);                                       \
    __builtin_amdgcn_s_barrier();                                            \
    __builtin_amdgcn_sched_barrier(0);                                       \
    LOADA(N0, N1, (T) + 2);                                                  \
    stageB(((T) + 2) % 3, (T) + 2);                                          \
    WRITEA(((T) + 1) % 3, C0, C1);                                           \
    compute((T) % 3);                                                        \
  } while (0)

__global__ __launch_bounds__(512, 2)
void k_gemm1(const float* __restrict__ X, const short* __restrict__ Bt,
             unsigned short* __restrict__ Cb) {
  __shared__ short As[3][128 * 32];
  __shared__ short Bs[3][256 * 32];
  const int tid = threadIdx.x, l = tid & 63, w = tid >> 6;
  const int nwg = gridDim.x, cpx = nwg >> 3;
  const int bid = (blockIdx.x & 7) * cpx + (blockIdx.x >> 3);
  const int mt = bid / 6, nt = bid % 6;
  const int m0 = mt << 7, n0 = nt * 256;
  const int wm = (w >> 2) << 6, wn = (w & 3) << 6;
  const int rowA = tid >> 2;                       // 128 rows x 4 slot-groups
  const int slA = (tid & 3) ^ ((rowA >> 1) & 3);   // source-side T2 swizzle

  f32x4 acc[4][4];
#pragma unroll
  for (int i = 0; i < 4; i++)
#pragma unroll
    for (int j = 0; j < 4; j++) acc[i][j] = (f32x4){0.f, 0.f, 0.f, 0.f};

  auto stageB = [&](int buf, int t) {
#pragma unroll
    for (int c = 0; c < 2; ++c) {
      int ch = tid + c * 512;                      // 1024 chunks: 256 rows x 4
      int row = ch >> 2;
      int sl = (ch & 3) ^ ((row >> 1) & 3);
      gload_lds16(Bt + (size_t)(n0 + row) * 384 + t * 32 + sl * 8, &Bs[buf][ch * 8]);
    }
  };
  const int sp8 = (((l >> 4) ^ ((l >> 1) & 3)) << 3);
  auto compute = [&](int buf) {
    bf16x8 af[4], bfr[4];
#pragma unroll
    for (int i = 0; i < 4; i++)
      af[i] = *(const bf16x8*)&As[buf][(wm + i * 16 + (l & 15)) * 32 + sp8];
#pragma unroll
    for (int j = 0; j < 4; j++)
      bfr[j] = *(const bf16x8*)&Bs[buf][(wn + j * 16 + (l & 15)) * 32 + sp8];
#pragma unroll
    for (int i = 0; i < 4; i++)
#pragma unroll
      for (int j = 0; j < 4; j++)
        acc[i][j] = __builtin_amdgcn_mfma_f32_16x16x32_bf16(af[i], bfr[j], acc[i][j], 0, 0, 0);
  };

  f32x4 a0_, a1_, b0_, b1_;
  // prologue FIFO: A(0)x2, A(1)x2, B(0)x2, B(1)x2 = 8 outstanding.
  LOADA(a0_, a1_, 0);
  LOADA(b0_, b1_, 1);
  stageB(0, 0);
  stageB(1, 1);
  asm volatile("s_waitcnt vmcnt(6)" ::: "memory");  // drain A(0)
  WRITEA(0, a0_, a1_);

#pragma unroll 1
  for (int tp = 0; tp < 10; tp += 2) {
    STEP_MAIN(tp,     b0_, b1_, a0_, a1_);
    STEP_MAIN(tp + 1, a0_, a1_, b0_, b1_);
  }
  // T=10: drain B(10)+A(11), write tile 11 (b set), no new issue.
  asm volatile("s_waitcnt vmcnt(2) lgkmcnt(0)" ::: "memory");
  __builtin_amdgcn_sched_barrier(0);
  __builtin_amdgcn_s_barrier();
  __builtin_amdgcn_sched_barrier(0);
  WRITEA(2, b0_, b1_);
  compute(1);
  // T=11
  asm volatile("s_waitcnt vmcnt(0) lgkmcnt(0)" ::: "memory");
  __builtin_amdgcn_sched_barrier(0);
  __builtin_amdgcn_s_barrier();
  __builtin_amdgcn_sched_barrier(0);
  compute(2);

#pragma unroll
  for (int i = 0; i < 4; i++) {
    int mrow = m0 + wm + i * 16 + ((l >> 4) << 2);
#pragma unroll
    for (int j = 0; j < 4; j++) {
      int ncol = n0 + wn + j * 16 + (l & 15);
#pragma unroll
      for (int r = 0; r < 4; r++)
        Cb[(size_t)(mrow + r) * 1536 + ncol] = f2bf(acc[i][j][r]);
    }
  }
}

// ---------------- GEMM2: out = O * Wot^T + bias ----------------------------
// 256x128 tile, 512 threads (8 waves, 4M x 2N), 3-buffer, counted vmcnt(3),
// T1+T2 swizzles. (r18 verified)

__global__ __launch_bounds__(512, 2)
void k_gemm2(const short* __restrict__ A, const short* __restrict__ Bt,
             float* __restrict__ Cf, const float* __restrict__ bias) {
  __shared__ short As[3][256 * 32];
  __shared__ short Bs[3][128 * 32];
  const int tid = threadIdx.x;
  const int l = tid & 63, w = tid >> 6;
  const int nwg = gridDim.x, cpx = nwg >> 3;
  const int bid = (blockIdx.x & 7) * cpx + (blockIdx.x >> 3);
  const int mt = bid / 3, nt = bid % 3;
  const int m0 = mt << 8, n0 = nt << 7;
  const int wm = (w >> 1) << 6, wn = (w & 1) << 6;

  f32x4 acc[4][4];
#pragma unroll
  for (int i = 0; i < 4; i++)
#pragma unroll
    for (int j = 0; j < 4; j++) acc[i][j] = (f32x4){0.f, 0.f, 0.f, 0.f};

  const int nsteps = 16;  // K=512 / 32

  auto stage = [&](int buf, int t) {
#pragma unroll
    for (int c = 0; c < 2; ++c) {
      int ch = tid + c * 512;
      int row = ch >> 2;
      int sl = (ch & 3) ^ ((row >> 1) & 3);
      gload_lds16(A + (size_t)(m0 + row) * 512 + t * 32 + sl * 8, &As[buf][ch * 8]);
    }
    {
      int ch = tid;
      int row = ch >> 2;
      int sl = (ch & 3) ^ ((row >> 1) & 3);
      gload_lds16(Bt + (size_t)(n0 + row) * 512 + t * 32 + sl * 8, &Bs[buf][ch * 8]);
    }
  };
  const int sp8 = (((l >> 4) ^ ((l >> 1) & 3)) << 3);
  auto compute = [&](int buf) {
    bf16x8 af[4], bfr[4];
#pragma unroll
    for (int i = 0; i < 4; i++)
      af[i] = *(const bf16x8*)&As[buf][(wm + i * 16 + (l & 15)) * 32 + sp8];
#pragma unroll
    for (int j = 0; j < 4; j++)
      bfr[j] = *(const bf16x8*)&Bs[buf][(wn + j * 16 + (l & 15)) * 32 + sp8];
#pragma unroll
    for (int i = 0; i < 4; i++)
#pragma unroll
      for (int j = 0; j < 4; j++)
        acc[i][j] = __builtin_amdgcn_mfma_f32_16x16x32_bf16(af[i], bfr[j], acc[i][j], 0, 0, 0);
  };

  stage(0, 0);
  stage(1, 1);
#pragma unroll 1
  for (int t = 0; t < nsteps; ++t) {
    if (t + 1 < nsteps) {
      asm volatile("s_waitcnt vmcnt(3)" ::: "memory");
    } else {
      asm volatile("s_waitcnt vmcnt(0)" ::: "memory");
    }
    __builtin_amdgcn_sched_barrier(0);
    __builtin_amdgcn_s_barrier();
    __builtin_amdgcn_sched_barrier(0);
    if (t + 2 < nsteps) stage((t + 2) % 3, t + 2);
    compute(t % 3);
  }

#pragma unroll
  for (int i = 0; i < 4; i++) {
    int mrow = m0 + wm + i * 16 + ((l >> 4) << 2);
#pragma unroll
    for (int j = 0; j < 4; j++) {
      int ncol = n0 + wn + j * 16 + (l & 15);
#pragma unroll
      for (int r = 0; r < 4; r++)
        Cf[(size_t)(mrow + r) * 384 + ncol] = acc[i][j][r] + bias[ncol];
    }
  }
}

// ---------------- fused attention per (bp, head) ----------------
// Swapped QK^T + pi-permuted V, eager bf16 pack, per-kc sched_barrier
// pressure clamp, T5 setprio around MFMA clusters. (r17 verified)

__global__ __launch_bounds__(512, 2)
void k_attn(const short* __restrict__ qkv, unsigned short* __restrict__ O) {
  __shared__ short Kl[256 * 64];
  __shared__ short Vt[64 * 256];

  const int tid = threadIdx.x, l = tid & 63, w = tid >> 6;
  const int g = (l >> 4) & 3;
  const int bh = blockIdx.x;
  const int bp = bh >> 3, h = bh & 7;
  const size_t tokbase = (size_t)bp * 256 * 1536;
  const int qoff = h * 64, koff = 512 + h * 64, voff = 1024 + h * 64;

#pragma unroll
  for (int c = 0; c < 4; ++c) {
    int ch = tid + c * 512;
    int row = ch >> 3, s = ch & 7;
    int sg = s ^ (row & 7);
    gload_lds16(qkv + tokbase + (size_t)row * 1536 + koff + sg * 8, &Kl[ch * 8]);
  }
#pragma unroll
  for (int c = 0; c < 4; ++c) {
    int ch = tid + c * 512;
    int row = ch >> 3, d0 = (ch & 7) * 8;
    short8 v = *(const short8*)(qkv + tokbase + (size_t)row * 1536 + voff + d0);
    int kc = row >> 5, u = row & 31;
    int gg = (u >> 2) & 3;
    int off = ((u & 16) ? 4 : 0) + (u & 3);
#pragma unroll
    for (int j = 0; j < 8; ++j) {
      int d = d0 + j;
      int sl = (kc * 4 + gg) ^ (d & 15);
      Vt[d * 256 + sl * 8 + off] = v[j];
    }
  }
  __syncthreads();

  const float CEXP = 0.125f * 1.44269504f;

#pragma unroll 1
  for (int it = 0; it < 2; ++it) {
    const int q0 = w * 32 + it * 16;
    bf16x8 qa[2];
#pragma unroll
    for (int dc = 0; dc < 2; ++dc)
      qa[dc] = *(const bf16x8*)(qkv + tokbase + (size_t)(q0 + (l & 15)) * 1536 + qoff +
                                dc * 32 + (l >> 4) * 8);
    f32x4 s[16];
#pragma unroll
    for (int kt = 0; kt < 16; kt++) s[kt] = (f32x4){0.f, 0.f, 0.f, 0.f};
    __builtin_amdgcn_s_setprio(1);
#pragma unroll
    for (int dc = 0; dc < 2; ++dc) {
#pragma unroll
      for (int kt = 0; kt < 16; ++kt) {
        int kcol = kt * 16 + (l & 15);
        int sl = (dc * 4 + (l >> 4)) ^ (kcol & 7);
        bf16x8 kb = *(const bf16x8*)&Kl[kcol * 64 + sl * 8];
        s[kt] = __builtin_amdgcn_mfma_f32_16x16x32_bf16(kb, qa[dc], s[kt], 0, 0, 0);
      }
    }
    __builtin_amdgcn_s_setprio(0);
    float mx = s[0][0];
#pragma unroll
    for (int kt = 0; kt < 16; kt++)
#pragma unroll
      for (int r = 0; r < 4; r++) mx = fmaxf(mx, s[kt][r]);
    mx = fmaxf(mx, __shfl_xor(mx, 16, 64));
    mx = fmaxf(mx, __shfl_xor(mx, 32, 64));

    u32x4 pa[8];
    float sum = 0.f;
#pragma unroll
    for (int kc = 0; kc < 8; ++kc) {
      float p0 = exp2f((s[2 * kc][0] - mx) * CEXP);
      float p1 = exp2f((s[2 * kc][1] - mx) * CEXP);
      float p2 = exp2f((s[2 * kc][2] - mx) * CEXP);
      float p3 = exp2f((s[2 * kc][3] - mx) * CEXP);
      float p4 = exp2f((s[2 * kc + 1][0] - mx) * CEXP);
      float p5 = exp2f((s[2 * kc + 1][1] - mx) * CEXP);
      float p6 = exp2f((s[2 * kc + 1][2] - mx) * CEXP);
      float p7 = exp2f((s[2 * kc + 1][3] - mx) * CEXP);
      sum += ((p0 + p1) + (p2 + p3)) + ((p4 + p5) + (p6 + p7));
      u32x4 pw;
      pw[0] = (unsigned)f2bf(p0) | ((unsigned)f2bf(p1) << 16);
      pw[1] = (unsigned)f2bf(p2) | ((unsigned)f2bf(p3) << 16);
      pw[2] = (unsigned)f2bf(p4) | ((unsigned)f2bf(p5) << 16);
      pw[3] = (unsigned)f2bf(p6) | ((unsigned)f2bf(p7) << 16);
      pa[kc] = pw;
    }
    sum += __shfl_xor(sum, 16, 64);
    sum += __shfl_xor(sum, 32, 64);
    float rs = 1.0f / sum;

    f32x4 o[4];
#pragma unroll
    for (int dt = 0; dt < 4; dt++) o[dt] = (f32x4){0.f, 0.f, 0.f, 0.f};
#pragma unroll
    for (int kc = 0; kc < 8; ++kc) {
      bf16x8 paf = __builtin_bit_cast(bf16x8, pa[kc]);
      __builtin_amdgcn_s_setprio(1);
#pragma unroll
      for (int dt = 0; dt < 4; ++dt) {
        int d = dt * 16 + (l & 15);
        int sl = (kc * 4 + g) ^ (d & 15);
        bf16x8 vb = *(const bf16x8*)&Vt[d * 256 + sl * 8];
        o[dt] = __builtin_amdgcn_mfma_f32_16x16x32_bf16(paf, vb, o[dt], 0, 0, 0);
      }
      __builtin_amdgcn_s_setprio(0);
      __builtin_amdgcn_sched_barrier(0);
    }
    float rsq[4];
#pragma unroll
    for (int r = 0; r < 4; ++r)
      rsq[r] = __shfl(rs, (l & 48) | (g * 4 + r), 64);
#pragma unroll
    for (int dt = 0; dt < 4; dt++) {
#pragma unroll
      for (int r = 0; r < 4; r++) {
        int qrow = q0 + g * 4 + r;
        int d = dt * 16 + (l & 15);
        O[(size_t)(bp * 256 + qrow) * 512 + h * 64 + d] = f2bf(o[dt][r] * rsq[r]);
      }
    }
  }
}

// ---------------- launch ----------------

extern "C" void kernel_launch(void* const* d_in, const int* in_sizes, int n_in,
                              void* d_out, int out_size, void* d_ws, size_t ws_size,
                              hipStream_t stream) {
  const float* x    = (const float*)d_in[0];
  const float* wqkv = (const float*)d_in[1];
  const float* wout = (const float*)d_in[2];
  const float* bout = (const float*)d_in[3];
  float* out = (float*)d_out;
  char* ws = (char*)d_ws;

  short* Wot = (short*)(ws);                          //   0.39 MB [384][512]
  short* Wqt = (short*)(ws + 25559040);               //   1.18 MB [1536][384]
  unsigned short* O = (unsigned short*)(ws + 393216); //  33.55 MB [32768][512]
  short* QKV = (short*)(ws + 33947648);               // 100.66 MB [32768][1536]

  k_prep<<<3072, 256, 0, stream>>>(wqkv, wout, Wqt, Wot);
  // GEMM1 (fused cast): 128x256 tiles -> 1536 blocks (%8==0)
  k_gemm1<<<1536, 512, 0, stream>>>(x, Wqt, (unsigned short*)QKV);
  k_attn<<<1024, 512, 0, stream>>>(QKV, O);
  // GEMM2: 256x128 tiles -> 384 blocks (%8==0)
  k_gemm2<<<384, 512, 0, stream>>>((const short*)O, Wot, out, bout);
  (void)in_sizes; (void)n_in; (void)out_size; (void)ws_size;
}